// Round 11
// baseline (107.436 us; speedup 1.0000x reference)
//
#include <hip/hip_runtime.h>
#include <hip/hip_bf16.h>
#include <cstdint>

typedef __attribute__((ext_vector_type(8))) short short8;
typedef __attribute__((ext_vector_type(4))) float f32x4;

#define BDIM 32
#define CDIM 2048
#define NPIX 196    // 14*14
#define HIN 14
#define N2 784      // 28*28
#define W2 28
#define KDIM 113
#define KC 112
#define NCLS 200
#define NBX 14      // col-blocks per image (2 output rows each)
#define BNC 56      // output cols per block
#define NT 4        // B tiles per block window (64 px >= any 42-px window)
#define NTILE 13    // px tiles per image (208 >= 196)
#define RDST 68     // RDs row stride (f32)
#define SST 60      // Ss row stride
#define NSTEP 64    // 2048/32
#define PST 224     // k_xt staged plane stride (196 + 28 pad for +15 reads)
#define GST 200     // Gram per-type stride

// ---------------- K_prep: concepts (+cfcw as row 113) -> bf16 pre-permuted + csq ----------------
__global__ __launch_bounds__(256) void k_prep(const float* __restrict__ concepts,
                                              const float* __restrict__ cfcw,
                                              ushort* __restrict__ cbf,
                                              float* __restrict__ csq) {
  int k = blockIdx.x, t = threadIdx.x;
  const int kt = k >> 4, lr = k & 15;
  float s = 0.f;
  for (int c = t; c < CDIM; c += 256) {
    float v = (k < KDIM) ? concepts[(size_t)k * CDIM + c] : (k == KDIM ? cfcw[c] : 0.f);
    __hip_bfloat16 h = __float2bfloat16(v);
    int st = c >> 5, gs = (c >> 3) & 3, j = c & 7;
    cbf[((((size_t)st * 8 + kt) * 4 + gs) * 16 + lr) * 8 + j] = __bfloat16_as_ushort(h);
    float vb = __bfloat162float(h);
    s = fmaf(vb, vb, s);
  }
  __shared__ float r[4];
#pragma unroll
  for (int off = 32; off > 0; off >>= 1) s += __shfl_down(s, off, 64);
  if ((t & 63) == 0) r[t >> 6] = s;
  __syncthreads();
  if (t == 0) csq[k] = r[0] + r[1] + r[2] + r[3];
}

// ---------------- K_xt: transpose x -> bf16 fragment image xt + Gram partials ----------------
// Block (sg, b): steps s = sg*4 .. sg*4+3 (channels s*32..s*32+31 each).
__global__ __launch_bounds__(512, 2) void k_xt(const float* __restrict__ x,
                                               ushort* __restrict__ xt,
                                               float* __restrict__ Gpart) {
  __shared__ float P[32 * PST];        // staged slice, ch-major (28.7 KB)
  __shared__ float Gw[8][16][65];      // per-wave Gram partials (33.3 KB)
  const int sg = blockIdx.x, b = blockIdx.y;
  const int tid = threadIdx.x;
  const int lane = tid & 63, wv = tid >> 6;
  const int chg = tid >> 4, seg = tid & 15;       // Gram mapping
  const int p0 = seg * 13;                         // 13 px per seg

  // zero pads once: P[ch][196..223]
  for (int z = tid; z < 32 * 28; z += 512) {
    int c = z / 28, j = z - c * 28;
    P[c * PST + 196 + j] = 0.f;
  }

  float g[13][5];
#pragma unroll
  for (int p = 0; p < 13; ++p)
#pragma unroll
    for (int t = 0; t < 5; ++t) g[p][t] = 0.f;

  for (int si = 0; si < 4; ++si) {
    const int s = sg * 4 + si;
    __syncthreads();
    // stage: 1568 float4 coalesced
    {
      const float4* src = (const float4*)(x + ((size_t)b * CDIM + s * 32) * NPIX);
#pragma unroll
      for (int i = 0; i < 3; ++i) {
        int q = tid + i * 512;
        int c = q / 49, pq = q - c * 49;
        *(float4*)&P[c * PST + 4 * pq] = src[q];
      }
      if (tid < 32) {
        int q = 1536 + tid;
        int c = q / 49, pq = q - c * 49;
        *(float4*)&P[c * PST + 4 * pq] = src[q];
      }
    }
    __syncthreads();
    // transpose -> xt (slots tid and tid+512)
#pragma unroll
    for (int it = 0; it < 2; ++it) {
      int slot = tid + it * 512;
      if (slot < NTILE * 64) {
        int t = slot >> 6, l = slot & 63;
        int px = t * 16 + (l & 15);
        int cl = (l >> 4) * 8;
        uint uu[4];
        if (px < NPIX) {
#pragma unroll
          for (int p = 0; p < 4; ++p) {
            float v0 = P[(cl + 2 * p) * PST + px];
            float v1 = P[(cl + 2 * p + 1) * PST + px];
            uu[p] = (uint)__bfloat16_as_ushort(__float2bfloat16(v0)) |
                    ((uint)__bfloat16_as_ushort(__float2bfloat16(v1)) << 16);
          }
        } else {
          uu[0] = uu[1] = uu[2] = uu[3] = 0u;
        }
        uint4 pk; pk.x = uu[0]; pk.y = uu[1]; pk.z = uu[2]; pk.w = uu[3];
        *(uint4*)&xt[((((size_t)b * NTILE + t) * 64 + s) << 9) + (size_t)l * 8] = pk;
      }
    }
    // Gram: thread (chg, seg) covers px p0..p0+12 of channel chg
    {
      float xv[28];
      const float* Pr = &P[chg * PST];
#pragma unroll
      for (int i = 0; i < 7; ++i) *(float4*)&xv[4 * i] = *(const float4*)&Pr[p0 + 4 * i];
#pragma unroll
      for (int p = 0; p < 13; ++p) {
        float a = xv[p];
        g[p][0] = fmaf(a, a, g[p][0]);
        g[p][1] = fmaf(a, xv[p + 1], g[p][1]);
        g[p][2] = fmaf(a, xv[p + 13], g[p][2]);
        g[p][3] = fmaf(a, xv[p + 14], g[p][3]);
        g[p][4] = fmaf(a, xv[p + 15], g[p][4]);
      }
    }
  }
  // reduce Gram over the wave's 4 channels
#pragma unroll
  for (int p = 0; p < 13; ++p)
#pragma unroll
    for (int t = 0; t < 5; ++t) {
      float v = g[p][t];
      v += __shfl_xor(v, 16, 64);
      v += __shfl_xor(v, 32, 64);
      g[p][t] = v;
    }
  if (lane < 16) {
#pragma unroll
    for (int p = 0; p < 13; ++p)
#pragma unroll
      for (int t = 0; t < 5; ++t) Gw[wv][lane][p * 5 + t] = g[p][t];
  }
  __syncthreads();
  // reduce over 8 waves -> Gpart[b][sg][type*GST+px]
#pragma unroll
  for (int it = 0; it < 2; ++it) {
    int slot = tid + it * 512;
    if (slot < 16 * 65) {
      int sseg = slot / 65, i = slot - sseg * 65;
      float v = 0.f;
#pragma unroll
      for (int ww = 0; ww < 8; ++ww) v += Gw[ww][sseg][i];
      int pl = i / 5, ty = i - pl * 5;
      int px = sseg * 13 + pl;
      if (px < NPIX)
        Gpart[((size_t)b * 16 + sg) * (5 * GST) + ty * GST + px] = v;
    }
  }
}

// ---------------- K_gred: Gs[b][5*GST] = sum over 16 sg ----------------
__global__ __launch_bounds__(256) void k_gred(const float* __restrict__ Gpart,
                                              float* __restrict__ Gs) {
  const int b = blockIdx.x, tid = threadIdx.x;
  for (int i = tid; i < 5 * GST; i += 256) {
    float v = 0.f;
#pragma unroll
    for (int sg = 0; sg < 16; ++sg) v += Gpart[((size_t)b * 16 + sg) * (5 * GST) + i];
    Gs[(size_t)b * (5 * GST) + i] = v;
  }
}

// ---------------- K_gemm2: barrier-free all-register MFMA + upsample/softmax epilogue ----------------
__global__ __launch_bounds__(512, 4) void k_gemm2(
    const ushort* __restrict__ xt,       // fragment-image bf16 x
    const ushort* __restrict__ cbf,      // fragment-image bf16 concepts (+cfcw row 113)
    const float* __restrict__ Gs,        // [32][5*GST] Gram
    const float* __restrict__ csq,       // [128]
    float* __restrict__ attn_out,        // [32][113][784]
    float* __restrict__ part)            // [32][14][112]
{
  __shared__ float RDs[128 * RDST];      // 34.8 KB
  __shared__ float Ss[KDIM * SST];       // 27.1 KB
  __shared__ float csq_s[KDIM];
  __shared__ float xsqs[BNC], projs[BNC];

  const int tid = threadIdx.x;
  // XCD-aware decode: all 14 col-blocks of image b on one XCD
  const int wgid = blockIdx.x;
  const int xcd = wgid & 7, slot = wgid >> 3;
  const int bq = slot / NBX;
  const int bx = slot - bq * NBX;
  const int b = xcd + 8 * bq;
  const int n0 = bx * BNC;
  const int lane = tid & 63, w = tid >> 6;       // wave = k-tile
  const int lr = lane & 15, gsn = lane >> 4;

  int r0 = bx - 1; if (r0 < 0) r0 = 0; if (r0 > 11) r0 = 11;
  const int t0 = (r0 * HIN) >> 4;                // window tiles t0..t0+3 (t0 <= 9)

  if (tid < KDIM) csq_s[tid] = csq[tid];

  const ushort* abp = cbf + w * 512 + lane * 8;
  const ushort* xtb = xt + (((size_t)b * NTILE + t0) << 15) + lane * 8;  // +tt*32768 + s*512

  f32x4 acc[NT];
#pragma unroll
  for (int t2 = 0; t2 < NT; ++t2) acc[t2] = f32x4{0.f, 0.f, 0.f, 0.f};

#define LOADSET(A_, B_, S_)                                              \
  do {                                                                   \
    const int s_ = (S_);                                                 \
    A_ = *(const uint4*)(abp + (size_t)s_ * 4096);                       \
    _Pragma("unroll")                                                    \
    for (int j_ = 0; j_ < NT; ++j_)                                      \
      B_[j_] = *(const uint4*)(xtb + ((size_t)j_ << 15) + (size_t)s_ * 512); \
  } while (0)

#define COMPUTE(A_, B_)                                                  \
  do {                                                                   \
    short8 af_ = *(const short8*)&A_;                                    \
    _Pragma("unroll")                                                    \
    for (int j_ = 0; j_ < NT; ++j_) {                                    \
      short8 bf_ = *(const short8*)&B_[j_];                              \
      acc[j_] = __builtin_amdgcn_mfma_f32_16x16x32_bf16(af_, bf_, acc[j_], 0, 0, 0); \
    }                                                                    \
  } while (0)

  uint4 a0, a1, b0[NT], b1[NT];
  LOADSET(a0, b0, 0);
  for (int s = 0; s < NSTEP; s += 2) {
    if (s + 1 < NSTEP) LOADSET(a1, b1, s + 1);
    COMPUTE(a0, b0);
    if (s + 2 < NSTEP) LOADSET(a0, b0, s + 2);
    COMPUTE(a1, b1);
  }
#undef LOADSET
#undef COMPUTE

  // ---- RDs: C layout col=lane&15, row=(lane>>4)*4+reg ----
#pragma unroll
  for (int tt = 0; tt < NT; ++tt)
#pragma unroll
    for (int q = 0; q < 4; ++q)
      RDs[(w * 16 + gsn * 4 + q) * RDST + tt * 16 + lr] = acc[tt][q];
  __syncthreads();

  // per-column folded bilinear taps (global pixel indices)
  auto COLW = [&](int col, int& p1g, int& p3g, float& w00, float& w01, float& w10, float& w11) {
    const int i2 = 2 * bx + (col >= 28 ? 1 : 0);
    const int j2 = col - (col >= 28 ? 28 : 0);
    float si = 0.5f * i2 - 0.25f, sj = 0.5f * j2 - 0.25f;
    float fif = floorf(si), fjf = floorf(sj);
    int ii = (int)fif, jj = (int)fjf;
    float fi = si - fif, fj = sj - fjf;
    int ia = ii < 0 ? 0 : ii; int ib = (ii + 1 > 13) ? 13 : ii + 1;
    int ja = jj < 0 ? 0 : jj; int jb = (jj + 1 > 13) ? 13 : jj + 1;
    w00 = (1.f - fi) * (1.f - fj); w01 = (1.f - fi) * fj;
    w10 = fi * (1.f - fj);         w11 = fi * fj;
    if (ib == ia) { w00 += w10; w01 += w11; w10 = 0.f; w11 = 0.f; }
    if (jb == ja) { w00 += w01; w10 += w11; w01 = 0.f; w11 = 0.f; }
    p1g = ia * HIN + ja; p3g = ib * HIN + ja;
  };

  // ---- xsq (Gram blend, global reads) + proj (RDs row 113) ----
  if (tid < BNC) {
    int p1g, p3g; float w00, w01, w10, w11;
    COLW(tid, p1g, p3g, w00, w01, w10, w11);
    const float* Gb = Gs + (size_t)b * (5 * GST);
    const float* Gd = Gb, *Gr = Gb + GST, *Gy = Gb + 2 * GST, *Gv = Gb + 3 * GST, *Gx = Gb + 4 * GST;
    float xsq = w00 * w00 * Gd[p1g] + w01 * w01 * Gd[p1g + 1]
              + w10 * w10 * Gd[p3g] + w11 * w11 * Gd[p3g + 1]
              + 2.f * (w00 * w01 * Gr[p1g] + w10 * w11 * Gr[p3g]
                     + w00 * w10 * Gv[p1g] + w01 * w11 * Gv[p1g + 1]
                     + w00 * w11 * Gx[p1g] + w01 * w10 * Gy[p1g + 1]);
    const int p1 = p1g - t0 * 16, p3 = p3g - t0 * 16;
    const float* rp = &RDs[113 * RDST];
    float pj = w00 * rp[p1] + w01 * rp[p1 + 1] + w10 * rp[p3] + w11 * rp[p3 + 1];
    xsqs[tid] = xsq; projs[tid] = pj;
  }
  __syncthreads();

  // ---- d2 -> -dist -> quad softmax (into Ss) ----
  if (tid < BNC * 4) {
    const int col = tid >> 2, sub = tid & 3;
    int p1g, p3g; float w00, w01, w10, w11;
    COLW(col, p1g, p3g, w00, w01, w10, w11);
    const int p1 = p1g - t0 * 16, p3 = p3g - t0 * 16;
    const float xq = xsqs[col];
    float mx = -1e30f;
    for (int k = sub; k < KDIM; k += 4) {
      const float* rk = &RDs[k * RDST];
      float dot = w00 * rk[p1] + w01 * rk[p1 + 1] + w10 * rk[p3] + w11 * rk[p3 + 1];
      float d2 = csq_s[k] + xq - 2.f * dot;
      float sv = -sqrtf(fmaxf(d2, 0.f));
      Ss[k * SST + col] = sv;
      mx = fmaxf(mx, sv);
    }
    mx = fmaxf(mx, __shfl_xor(mx, 1, 64));
    mx = fmaxf(mx, __shfl_xor(mx, 2, 64));
    float ssum = 0.f;
    for (int k = sub; k < KDIM; k += 4) {
      float e = __expf(Ss[k * SST + col] - mx);
      Ss[k * SST + col] = e;
      ssum += e;
    }
    ssum += __shfl_xor(ssum, 1, 64);
    ssum += __shfl_xor(ssum, 2, 64);
    const float rinv = 1.f / ssum;
    for (int k = sub; k < KDIM; k += 4) Ss[k * SST + col] *= rinv;
  }
  __syncthreads();

  // ---- coalesced attn write ----
  {
    const int col2 = tid & 63, kr = tid >> 6;
    if (col2 < BNC) {
      float* op = attn_out + (size_t)b * KDIM * N2 + n0 + col2;
      for (int k = kr; k < KDIM; k += 8) op[(size_t)k * N2] = Ss[k * SST + col2];
    }
  }

  // ---- logit partials ----
  if (tid < KC * 4) {
    const int k = tid >> 2, sub = tid & 3;
    float lg = 0.f;
    for (int c2 = sub; c2 < BNC; c2 += 4) lg = fmaf(Ss[k * SST + c2], projs[c2], lg);
    lg += __shfl_xor(lg, 1, 64);
    lg += __shfl_xor(lg, 2, 64);
    if (sub == 0) part[((size_t)b * NBX + bx) * KC + k] = lg;
  }
}

// ---------------- K4: reduce partials -> sigmoid -> concept_scores ----------------
__global__ void k_sig(const float* __restrict__ part, const float* __restrict__ cfcb,
                      float* __restrict__ cs_out) {
  int i = blockIdx.x * blockDim.x + threadIdx.x;
  if (i >= BDIM * KC) return;
  int b = i / KC, k = i % KC;
  float l = cfcb[0];
#pragma unroll
  for (int t = 0; t < NBX; ++t) l += part[((size_t)b * NBX + t) * KC + k];
  cs_out[i] = 1.f / (1.f + __expf(-l));
}

// ---------------- K5a: tmp[b,c] = sum_k cs[b,k] * concepts[k,c] ----------------
__global__ __launch_bounds__(256) void k_tmp(
    const float* __restrict__ concepts, const float* __restrict__ cs,
    float* __restrict__ tmp) {
  __shared__ float cs_s[KC];
  const int b = blockIdx.y;
  const int c = blockIdx.x * 256 + threadIdx.x;
  if (threadIdx.x < KC) cs_s[threadIdx.x] = cs[b * KC + threadIdx.x];
  __syncthreads();
  float a = 0.f;
#pragma unroll 8
  for (int k = 0; k < KC; ++k) a = fmaf(cs_s[k], concepts[(size_t)k * CDIM + c], a);
  tmp[(size_t)b * CDIM + c] = a;
}

// ---------------- K5b: preds[b,cls] = tmp[b,:].labw[cls,:] + labb ----------------
__global__ __launch_bounds__(256) void k_pred2(
    const float* __restrict__ labw, const float* __restrict__ labb,
    const float* __restrict__ tmp, float* __restrict__ preds) {
  const int w = blockIdx.x * 4 + (threadIdx.x >> 6);
  const int lane = threadIdx.x & 63;
  const int b = w / NCLS, cls = w % NCLS;
  if (b >= BDIM) return;
  const float* tr = tmp + (size_t)b * CDIM;
  const float* wr = labw + (size_t)cls * CDIM;
  float a = 0.f;
#pragma unroll
  for (int c0 = 0; c0 < CDIM; c0 += 256) {
    float4 t = *(const float4*)&tr[c0 + lane * 4];
    float4 v = *(const float4*)&wr[c0 + lane * 4];
    a += t.x * v.x + t.y * v.y + t.z * v.z + t.w * v.w;
  }
#pragma unroll
  for (int off = 32; off > 0; off >>= 1) a += __shfl_down(a, off, 64);
  if (lane == 0) preds[b * NCLS + cls] = a + labb[cls];
}

extern "C" void kernel_launch(void* const* d_in, const int* in_sizes, int n_in,
                              void* d_out, int out_size, void* d_ws, size_t ws_size,
                              hipStream_t stream) {
  const float* x        = (const float*)d_in[0];
  const float* concepts = (const float*)d_in[1];
  const float* cfcw     = (const float*)d_in[2];
  const float* cfcb     = (const float*)d_in[3];
  const float* labw     = (const float*)d_in[4];
  const float* labb     = (const float*)d_in[5];

  float* out    = (float*)d_out;
  float* sm_out = out;                                  // [32][113][784]
  float* cs_out = out + (size_t)BDIM * KDIM * N2;       // [32][112]
  float* pr_out = cs_out + (size_t)BDIM * KC;           // [32][200]

  char* ws = (char*)d_ws;
  float*  csq   = (float*)(ws + 0);          // 128 f32             512 B
  float*  part  = (float*)(ws + 512);        // 32*14*112 f32       200,704 B
  ushort* cbf   = (ushort*)(ws + 201216);    // 128*2048 bf16       524,288 B
  float*  tmp   = (float*)(ws + 725504);     // 32*2048 f32         262,144 B
  float*  Gpart = (float*)(ws + 987648);     // 32*16*1000 f32      2,048,000 B
  float*  Gs    = (float*)(ws + 3035648);    // 32*1000 f32         128,000 B
  ushort* xt    = (ushort*)(ws + 3163648);   // 32*13*64*512 bf16   27,262,976 B

  k_prep <<<dim3(128), dim3(256), 0, stream>>>(concepts, cfcw, cbf, csq);
  k_xt   <<<dim3(16, BDIM), dim3(512), 0, stream>>>(x, xt, Gpart);
  k_gred <<<dim3(BDIM), dim3(256), 0, stream>>>(Gpart, Gs);
  k_gemm2<<<dim3(448), dim3(512), 0, stream>>>(xt, cbf, Gs, csq, sm_out, part);
  k_sig  <<<dim3((BDIM * KC + 255) / 256), dim3(256), 0, stream>>>(part, cfcb, cs_out);
  k_tmp  <<<dim3(CDIM / 256, BDIM), dim3(256), 0, stream>>>(concepts, cs_out, tmp);
  k_pred2<<<dim3((BDIM * NCLS + 3) / 4), dim3(256), 0, stream>>>(labw, labb, tmp, pr_out);
}

// Round 13
// 90.417 us; speedup vs baseline: 1.1882x; 1.1882x over previous
//
#include <hip/hip_runtime.h>
#include <hip/hip_bf16.h>
#include <cstdint>

typedef __attribute__((ext_vector_type(8))) short short8;
typedef __attribute__((ext_vector_type(4))) float f32x4;
typedef __attribute__((ext_vector_type(16))) float f32x16;

#define BDIM 32
#define CDIM 2048
#define NPIX 196    // 14*14
#define HIN 14
#define N2 784      // 28*28
#define W2 28
#define KDIM 113
#define KC 112
#define NCLS 200
#define NBX 14      // col-blocks per image (2 output rows each)
#define BNC 56      // output cols per block
#define NSTEP 64    // 2048/32
#define PST 224     // k_xt staged plane stride (196 + 28 pad)
#define GST 200     // Gram per-type stride
#define RDST 68     // RDs row stride (f32)
#define SSTB 60     // Ssb row stride (ushort)

// ---------------- K_prep: concepts (+cfcw row 113) -> bf16 in 32x32x16 A-fragment order + csq ----
__global__ __launch_bounds__(256) void k_prep(const float* __restrict__ concepts,
                                              const float* __restrict__ cfcw,
                                              ushort* __restrict__ cbf,
                                              float* __restrict__ csq) {
  int k = blockIdx.x, t = threadIdx.x;
  const int kt = k >> 5, row = k & 31;
  float s = 0.f;
  for (int c = t; c < CDIM; c += 256) {
    float v = (k < KDIM) ? concepts[(size_t)k * CDIM + c] : (k == KDIM ? cfcw[c] : 0.f);
    __hip_bfloat16 h = __float2bfloat16(v);
    int st = c >> 5, it = (c >> 4) & 1, g2 = (c >> 3) & 1, j = c & 7;
    cbf[(((size_t)st * 4 + kt) * 2 + it) * 512 + (g2 * 32 + row) * 8 + j] = __bfloat16_as_ushort(h);
    float vb = __bfloat162float(h);
    s = fmaf(vb, vb, s);
  }
  __shared__ float r[4];
#pragma unroll
  for (int off = 32; off > 0; off >>= 1) s += __shfl_down(s, off, 64);
  if ((t & 63) == 0) r[t >> 6] = s;
  __syncthreads();
  if (t == 0) csq[k] = r[0] + r[1] + r[2] + r[3];
}

// ---------------- K_xt: transpose x -> bf16 32x32x16 B-fragment image (16-padded rows) + Gram ----
__global__ __launch_bounds__(512, 2) void k_xt(const float* __restrict__ x,
                                               ushort* __restrict__ xt,
                                               float* __restrict__ Gpart) {
  __shared__ float P[32 * PST];        // 28.7 KB
  __shared__ float Gw[8][16][65];      // 33.3 KB
  const int sg = blockIdx.x, b = blockIdx.y;
  const int tid = threadIdx.x;
  const int lane = tid & 63, wv = tid >> 6;
  const int chg = tid >> 4, seg = tid & 15;
  const int p0 = seg * 13;

  for (int z = tid; z < 32 * 28; z += 512) {
    int c = z / 28, j = z - c * 28;
    P[c * PST + 196 + j] = 0.f;
  }

  float g[13][5];
#pragma unroll
  for (int p = 0; p < 13; ++p)
#pragma unroll
    for (int t = 0; t < 5; ++t) g[p][t] = 0.f;

  for (int si = 0; si < 4; ++si) {
    const int s = sg * 4 + si;
    __syncthreads();
    {
      const float4* src = (const float4*)(x + ((size_t)b * CDIM + s * 32) * NPIX);
#pragma unroll
      for (int i = 0; i < 3; ++i) {
        int q = tid + i * 512;
        int c = q / 49, pq = q - c * 49;
        *(float4*)&P[c * PST + 4 * pq] = src[q];
      }
      if (tid < 32) {
        int q = 1536 + tid;
        int c = q / 49, pq = q - c * 49;
        *(float4*)&P[c * PST + 4 * pq] = src[q];
      }
    }
    __syncthreads();
#pragma unroll
    for (int pass = 0; pass < 2; ++pass) {
      int slot = tid + pass * 512;
      if (slot < 896) {
        int t = slot >> 7, r = slot & 127;
        int it = r >> 6, l = r & 63;
        int pxp = t * 32 + (l & 31);
        int row = pxp >> 4, col = pxp & 15;
        int c0 = it * 16 + (l >> 5) * 8;
        uint uu[4];
        if (col < 14) {
          int px = row * HIN + col;
#pragma unroll
          for (int p = 0; p < 4; ++p) {
            float v0 = P[(c0 + 2 * p) * PST + px];
            float v1 = P[(c0 + 2 * p + 1) * PST + px];
            uu[p] = (uint)__bfloat16_as_ushort(__float2bfloat16(v0)) |
                    ((uint)__bfloat16_as_ushort(__float2bfloat16(v1)) << 16);
          }
        } else {
          uu[0] = uu[1] = uu[2] = uu[3] = 0u;
        }
        uint4 pk; pk.x = uu[0]; pk.y = uu[1]; pk.z = uu[2]; pk.w = uu[3];
        *(uint4*)&xt[((((size_t)b * 7 + t) * 64 + s) * 1024) + it * 512 + (size_t)l * 8] = pk;
      }
    }
    {
      float xv[28];
      const float* Pr = &P[chg * PST];
#pragma unroll
      for (int i = 0; i < 7; ++i) *(float4*)&xv[4 * i] = *(const float4*)&Pr[p0 + 4 * i];
#pragma unroll
      for (int p = 0; p < 13; ++p) {
        float a = xv[p];
        g[p][0] = fmaf(a, a, g[p][0]);
        g[p][1] = fmaf(a, xv[p + 1], g[p][1]);
        g[p][2] = fmaf(a, xv[p + 13], g[p][2]);
        g[p][3] = fmaf(a, xv[p + 14], g[p][3]);
        g[p][4] = fmaf(a, xv[p + 15], g[p][4]);
      }
    }
  }
#pragma unroll
  for (int p = 0; p < 13; ++p)
#pragma unroll
    for (int t = 0; t < 5; ++t) {
      float v = g[p][t];
      v += __shfl_xor(v, 16, 64);
      v += __shfl_xor(v, 32, 64);
      g[p][t] = v;
    }
  if (lane < 16) {
#pragma unroll
    for (int p = 0; p < 13; ++p)
#pragma unroll
      for (int t = 0; t < 5; ++t) Gw[wv][lane][p * 5 + t] = g[p][t];
  }
  __syncthreads();
#pragma unroll
  for (int it = 0; it < 2; ++it) {
    int slot = tid + it * 512;
    if (slot < 16 * 65) {
      int sseg = slot / 65, i = slot - sseg * 65;
      float v = 0.f;
#pragma unroll
      for (int ww = 0; ww < 8; ++ww) v += Gw[ww][sseg][i];
      int pl = i / 5, ty = i - pl * 5;
      int px = sseg * 13 + pl;
      if (px < NPIX)
        Gpart[((size_t)b * 16 + sg) * (5 * GST) + ty * GST + px] = v;
    }
  }
}

// ---------------- K_gred ----------------
__global__ __launch_bounds__(256) void k_gred(const float* __restrict__ Gpart,
                                              float* __restrict__ Gs) {
  const int b = blockIdx.x, tid = threadIdx.x;
  for (int i = tid; i < 5 * GST; i += 256) {
    float v = 0.f;
#pragma unroll
    for (int sg = 0; sg < 16; ++sg) v += Gpart[((size_t)b * 16 + sg) * (5 * GST) + i];
    Gs[(size_t)b * (5 * GST) + i] = v;
  }
}

// ---------------- K_gemm3: 32x32x16 barrier-free MFMA + reg epilogue (uniform barriers only) ----
__global__ __launch_bounds__(256, 3) void k_gemm3(
    const ushort* __restrict__ xt,
    const ushort* __restrict__ cbf,
    const float* __restrict__ Gs,
    const float* __restrict__ csq,
    float* __restrict__ attn_out,
    float* __restrict__ part)
{
  __shared__ float RDs[128 * RDST];      // 34.8 KB
  __shared__ ushort Ssb[KDIM * SSTB];    // 13.6 KB
  __shared__ float csq_s[KDIM];
  __shared__ float xsqs[BNC], projs2[BNC];

  const int tid = threadIdx.x;
  const int wgid = blockIdx.x;
  const int xcd = wgid & 7, slot = wgid >> 3;
  const int bq = slot / NBX, bx = slot - bq * NBX;
  const int b = xcd + 8 * bq;
  const int n0 = bx * BNC;
  const int lane = tid & 63, w = tid >> 6;   // wave w = k-rows 32w..32w+31

  int r0 = bx - 1; if (r0 < 0) r0 = 0; if (r0 > 11) r0 = 11;
  const int T0 = r0 >> 1;                    // window = px' tiles T0, T0+1

  if (tid < KDIM) csq_s[tid] = csq[tid];

  const ushort* abp = cbf + w * 1024 + lane * 8;                    // + s*4096 + it*512
  const ushort* xtb = xt + (((size_t)b * 7 + T0) << 16) + lane * 8; // + tt*65536 + s*1024 + it*512

  f32x16 acc[2];
#pragma unroll
  for (int tt = 0; tt < 2; ++tt)
#pragma unroll
    for (int r = 0; r < 16; ++r) acc[tt][r] = 0.f;

#define LOADSET(A_, B_, S_)                                              \
  do {                                                                   \
    const size_t so_ = (size_t)(S_) * 4096;                              \
    const size_t xo_ = (size_t)(S_) * 1024;                              \
    A_[0] = *(const uint4*)(abp + so_);                                  \
    A_[1] = *(const uint4*)(abp + so_ + 512);                            \
    B_[0][0] = *(const uint4*)(xtb + xo_);                               \
    B_[0][1] = *(const uint4*)(xtb + xo_ + 512);                         \
    B_[1][0] = *(const uint4*)(xtb + 65536 + xo_);                       \
    B_[1][1] = *(const uint4*)(xtb + 65536 + xo_ + 512);                 \
  } while (0)

#define COMPUTE(A_, B_)                                                  \
  do {                                                                   \
    _Pragma("unroll")                                                    \
    for (int it_ = 0; it_ < 2; ++it_) {                                  \
      short8 af_ = *(const short8*)&A_[it_];                             \
      acc[0] = __builtin_amdgcn_mfma_f32_32x32x16_bf16(                  \
          af_, *(const short8*)&B_[0][it_], acc[0], 0, 0, 0);            \
      acc[1] = __builtin_amdgcn_mfma_f32_32x32x16_bf16(                  \
          af_, *(const short8*)&B_[1][it_], acc[1], 0, 0, 0);            \
    }                                                                    \
  } while (0)

  uint4 a0[2], a1[2], b0[2][2], b1[2][2];
  LOADSET(a0, b0, 0);
  for (int s = 0; s < NSTEP; s += 2) {
    if (s + 1 < NSTEP) LOADSET(a1, b1, s + 1);
    COMPUTE(a0, b0);
    if (s + 2 < NSTEP) LOADSET(a0, b0, s + 2);
    COMPUTE(a1, b1);
  }
#undef LOADSET
#undef COMPUTE

  // ---- RDs: 32x32 C/D layout col=lane&31, row=(r&3)+8*(r>>2)+4*(lane>>5) ----
#pragma unroll
  for (int tt = 0; tt < 2; ++tt)
#pragma unroll
    for (int r = 0; r < 16; ++r) {
      int row = w * 32 + (r & 3) + 8 * (r >> 2) + 4 * (lane >> 5);
      RDs[row * RDST + tt * 32 + (lane & 31)] = acc[tt][r];
    }
  __syncthreads();

  auto COLW = [&](int col, int& p1, int& p3, int& p1g, int& p3g,
                  float& w00, float& w01, float& w10, float& w11) {
    const int i2 = 2 * bx + (col >= 28 ? 1 : 0);
    const int j2 = col - (col >= 28 ? 28 : 0);
    float si = 0.5f * i2 - 0.25f, sj = 0.5f * j2 - 0.25f;
    float fif = floorf(si), fjf = floorf(sj);
    int ii = (int)fif, jj = (int)fjf;
    float fi = si - fif, fj = sj - fjf;
    int ia = ii < 0 ? 0 : ii; int ib = (ii + 1 > 13) ? 13 : ii + 1;
    int ja = jj < 0 ? 0 : jj; int jb = (jj + 1 > 13) ? 13 : jj + 1;
    w00 = (1.f - fi) * (1.f - fj); w01 = (1.f - fi) * fj;
    w10 = fi * (1.f - fj);         w11 = fi * fj;
    if (ib == ia) { w00 += w10; w01 += w11; w10 = 0.f; w11 = 0.f; }
    if (jb == ja) { w00 += w01; w10 += w11; w01 = 0.f; w11 = 0.f; }
    p1g = ia * HIN + ja; p3g = ib * HIN + ja;
    p1 = ia * 16 + ja - T0 * 32; p3 = ib * 16 + ja - T0 * 32;
  };

  // ---- xsq (Gram blend) + raw proj (RDs row 113) ----
  if (tid < BNC) {
    int p1, p3, p1g, p3g; float w00, w01, w10, w11;
    COLW(tid, p1, p3, p1g, p3g, w00, w01, w10, w11);
    const float* Gb = Gs + (size_t)b * (5 * GST);
    const float* Gd = Gb, *Gr = Gb + GST, *Gy = Gb + 2 * GST, *Gv = Gb + 3 * GST, *Gx = Gb + 4 * GST;
    float xsq = w00 * w00 * Gd[p1g] + w01 * w01 * Gd[p1g + 1]
              + w10 * w10 * Gd[p3g] + w11 * w11 * Gd[p3g + 1]
              + 2.f * (w00 * w01 * Gr[p1g] + w10 * w11 * Gr[p3g]
                     + w00 * w10 * Gv[p1g] + w01 * w11 * Gv[p1g + 1]
                     + w00 * w11 * Gx[p1g] + w01 * w10 * Gy[p1g + 1]);
    const float* rp = &RDs[113 * RDST];
    float pj = w00 * rp[p1] + w01 * rp[p1 + 1] + w10 * rp[p3] + w11 * rp[p3 + 1];
    xsqs[tid] = xsq; projs2[tid] = pj;
  }
  __syncthreads();

  // ---- dist (regs) -> quad softmax -> attn write (local rinv) + Ssb; NO divergent barrier ----
  if (tid < BNC * 4) {
    const int col = tid >> 2, sub = tid & 3;
    int p1, p3, p1g, p3g; float w00, w01, w10, w11;
    COLW(col, p1, p3, p1g, p3g, w00, w01, w10, w11);
    const float xq = xsqs[col];
    float ev[29];
    float mx = -1e30f;
#pragma unroll
    for (int i = 0; i < 29; ++i) {
      int k = sub + 4 * i;
      if (k < KDIM) {
        const float* rk = &RDs[k * RDST];
        float dot = w00 * rk[p1] + w01 * rk[p1 + 1] + w10 * rk[p3] + w11 * rk[p3 + 1];
        float d2 = csq_s[k] + xq - 2.f * dot;
        float sv = -sqrtf(fmaxf(d2, 0.f));
        ev[i] = sv;
        mx = fmaxf(mx, sv);
      }
    }
    mx = fmaxf(mx, __shfl_xor(mx, 1, 64));
    mx = fmaxf(mx, __shfl_xor(mx, 2, 64));
    float ssum = 0.f;
#pragma unroll
    for (int i = 0; i < 29; ++i) {
      int k = sub + 4 * i;
      if (k < KDIM) {
        float e = __expf(ev[i] - mx);
        ev[i] = e;
        Ssb[k * SSTB + col] = __bfloat16_as_ushort(__float2bfloat16(e));
        ssum += e;
      }
    }
    ssum += __shfl_xor(ssum, 1, 64);
    ssum += __shfl_xor(ssum, 2, 64);
    const float rinv = 1.f / ssum;          // every quad thread has it locally
    // attn write from f32 regs (coalesced across col threads per k-row)
    float* op = attn_out + (size_t)b * KDIM * N2 + n0 + col;
#pragma unroll
    for (int i = 0; i < 29; ++i) {
      int k = sub + 4 * i;
      if (k < KDIM) op[(size_t)k * N2] = ev[i] * rinv;
    }
    if (sub == 0) projs2[col] *= rinv;
  }
  __syncthreads();   // UNIFORM barrier: Ssb + projs2 visible to all

  // ---- logit partials: Ssb (bf16 e) x (rinv*proj) ----
  if (tid < KC * 2) {
    const int k = tid >> 1, s2 = tid & 1;
    float lg = 0.f;
    for (int c2 = s2; c2 < BNC; c2 += 2)
      lg = fmaf(__uint_as_float((uint)Ssb[k * SSTB + c2] << 16), projs2[c2], lg);
    lg += __shfl_xor(lg, 1, 64);
    if (s2 == 0) part[((size_t)b * NBX + bx) * KC + k] = lg;
  }
}

// ---------------- K_tmp (+sig fused): cs inline, tmp[b,c] ----------------
__global__ __launch_bounds__(256) void k_tmp(
    const float* __restrict__ concepts, const float* __restrict__ part,
    const float* __restrict__ cfcb, float* __restrict__ cs_out,
    float* __restrict__ tmp) {
  __shared__ float cs_s[KC];
  const int b = blockIdx.y, cx = blockIdx.x;
  const int t = threadIdx.x;
  if (t < KC) {
    float l = cfcb[0];
#pragma unroll
    for (int q = 0; q < NBX; ++q) l += part[((size_t)b * NBX + q) * KC + t];
    float csv = 1.f / (1.f + __expf(-l));
    cs_s[t] = csv;
    if (cx == 0) cs_out[b * KC + t] = csv;
  }
  __syncthreads();
  const int c = cx * 256 + t;
  float a = 0.f;
#pragma unroll 8
  for (int k = 0; k < KC; ++k) a = fmaf(cs_s[k], concepts[(size_t)k * CDIM + c], a);
  tmp[(size_t)b * CDIM + c] = a;
}

// ---------------- K5b: preds ----------------
__global__ __launch_bounds__(256) void k_pred2(
    const float* __restrict__ labw, const float* __restrict__ labb,
    const float* __restrict__ tmp, float* __restrict__ preds) {
  const int w = blockIdx.x * 4 + (threadIdx.x >> 6);
  const int lane = threadIdx.x & 63;
  const int b = w / NCLS, cls = w % NCLS;
  if (b >= BDIM) return;
  const float* tr = tmp + (size_t)b * CDIM;
  const float* wr = labw + (size_t)cls * CDIM;
  float a = 0.f;
#pragma unroll
  for (int c0 = 0; c0 < CDIM; c0 += 256) {
    float4 t = *(const float4*)&tr[c0 + lane * 4];
    float4 v = *(const float4*)&wr[c0 + lane * 4];
    a += t.x * v.x + t.y * v.y + t.z * v.z + t.w * v.w;
  }
#pragma unroll
  for (int off = 32; off > 0; off >>= 1) a += __shfl_down(a, off, 64);
  if (lane == 0) preds[b * NCLS + cls] = a + labb[cls];
}

extern "C" void kernel_launch(void* const* d_in, const int* in_sizes, int n_in,
                              void* d_out, int out_size, void* d_ws, size_t ws_size,
                              hipStream_t stream) {
  const float* x        = (const float*)d_in[0];
  const float* concepts = (const float*)d_in[1];
  const float* cfcw     = (const float*)d_in[2];
  const float* cfcb     = (const float*)d_in[3];
  const float* labw     = (const float*)d_in[4];
  const float* labb     = (const float*)d_in[5];

  float* out    = (float*)d_out;
  float* sm_out = out;                                  // [32][113][784]
  float* cs_out = out + (size_t)BDIM * KDIM * N2;       // [32][112]
  float* pr_out = cs_out + (size_t)BDIM * KC;           // [32][200]

  char* ws = (char*)d_ws;
  float*  csq   = (float*)(ws + 0);          // 128 f32             512 B
  float*  part  = (float*)(ws + 512);        // 32*14*112 f32       200,704 B
  ushort* cbf   = (ushort*)(ws + 201216);    // 128*2048 bf16       524,288 B
  float*  tmp   = (float*)(ws + 725504);     // 32*2048 f32         262,144 B
  float*  Gpart = (float*)(ws + 987648);     // 32*16*1000 f32      2,048,000 B
  float*  Gs    = (float*)(ws + 3035648);    // 32*1000 f32         128,000 B
  ushort* xt    = (ushort*)(ws + 3163648);   // 32*7*64*1024 bf16   29,360,128 B

  k_prep <<<dim3(128), dim3(256), 0, stream>>>(concepts, cfcw, cbf, csq);
  k_xt   <<<dim3(16, BDIM), dim3(512), 0, stream>>>(x, xt, Gpart);
  k_gred <<<dim3(BDIM), dim3(256), 0, stream>>>(Gpart, Gs);
  k_gemm3<<<dim3(448), dim3(256), 0, stream>>>(xt, cbf, Gs, csq, sm_out, part);
  k_tmp  <<<dim3(CDIM / 256, BDIM), dim3(256), 0, stream>>>(concepts, part, cfcb, cs_out, tmp);
  k_pred2<<<dim3((BDIM * NCLS + 3) / 4), dim3(256), 0, stream>>>(labw, labb, tmp, pr_out);
}

// Round 14
// 84.703 us; speedup vs baseline: 1.2684x; 1.0675x over previous
//
#include <hip/hip_runtime.h>
#include <hip/hip_bf16.h>
#include <cstdint>

typedef __attribute__((ext_vector_type(8))) short short8;
typedef __attribute__((ext_vector_type(4))) float f32x4;
typedef __attribute__((ext_vector_type(16))) float f32x16;

#define BDIM 32
#define CDIM 2048
#define NPIX 196    // 14*14
#define HIN 14
#define N2 784      // 28*28
#define W2 28
#define KDIM 113
#define KC 112
#define NCLS 200
#define NBX 14      // col-blocks per image (2 output rows each)
#define BNC 56      // output cols per block
#define NSTEP 64    // 2048/32
#define PST 224     // k_xt staged plane stride (196 + 28 pad)
#define GST 200     // Gram per-type stride
#define RDST 68     // RDs row stride (f32)
#define SSTB 60     // Ssb row stride (ushort)

// ---------------- K_prep: concepts (+cfcw row 113) -> bf16 in 32x32x16 A-fragment order + csq ----
__global__ __launch_bounds__(256) void k_prep(const float* __restrict__ concepts,
                                              const float* __restrict__ cfcw,
                                              ushort* __restrict__ cbf,
                                              float* __restrict__ csq) {
  int k = blockIdx.x, t = threadIdx.x;
  const int kt = k >> 5, row = k & 31;
  float s = 0.f;
  for (int c = t; c < CDIM; c += 256) {
    float v = (k < KDIM) ? concepts[(size_t)k * CDIM + c] : (k == KDIM ? cfcw[c] : 0.f);
    __hip_bfloat16 h = __float2bfloat16(v);
    int st = c >> 5, it = (c >> 4) & 1, g2 = (c >> 3) & 1, j = c & 7;
    cbf[(((size_t)st * 4 + kt) * 2 + it) * 512 + (g2 * 32 + row) * 8 + j] = __bfloat16_as_ushort(h);
    float vb = __bfloat162float(h);
    s = fmaf(vb, vb, s);
  }
  __shared__ float r[4];
#pragma unroll
  for (int off = 32; off > 0; off >>= 1) s += __shfl_down(s, off, 64);
  if ((t & 63) == 0) r[t >> 6] = s;
  __syncthreads();
  if (t == 0) csq[k] = r[0] + r[1] + r[2] + r[3];
}

// ---------------- K_xt: async-split, double-buffered transpose + Gram ----------------
// Per si: issue loads(si+1) -> transpose+Gram(P[cur]) -> write regs->P[nxt] -> 1 barrier.
__global__ __launch_bounds__(512, 4) void k_xt(const float* __restrict__ x,
                                               ushort* __restrict__ xt,
                                               float* __restrict__ Gpart) {
  __shared__ float P[2][32 * PST];     // 57.3 KB double-buffered; reused as Gw after loop
  const int sg = blockIdx.x, b = blockIdx.y;
  const int tid = threadIdx.x;
  const int lane = tid & 63, wv = tid >> 6;
  const int chg = tid >> 4, seg = tid & 15;
  const int p0 = seg * 13;

  // staging index precompute (1568 float4 per slice; thread covers 3 [+1 if tid<32])
  const int c0a = tid / 49,           pq0 = tid - c0a * 49;
  const int c1a = (tid + 512) / 49,   pq1 = (tid + 512) - c1a * 49;
  const int c2a = (tid + 1024) / 49,  pq2 = (tid + 1024) - c2a * 49;
  const int c3a = (tid + 1536) / 49,  pq3 = (tid + 1536) - c3a * 49;  // tid<32 only

  // zero pads in BOTH buffers: P[buf][c][196..223]
  for (int z = tid; z < 2 * 32 * 28; z += 512) {
    int buf = z / 896, r = z - buf * 896;
    int c = r / 28, j = r - c * 28;
    P[buf][c * PST + 196 + j] = 0.f;
  }

  float g[13][5];
#pragma unroll
  for (int p = 0; p < 13; ++p)
#pragma unroll
    for (int t = 0; t < 5; ++t) g[p][t] = 0.f;

  float4 q0, q1, q2, q3 = {0.f, 0.f, 0.f, 0.f};
  auto LOADQ = [&](int s) {
    const float4* src = (const float4*)(x + ((size_t)b * CDIM + s * 32) * NPIX);
    q0 = src[tid]; q1 = src[tid + 512]; q2 = src[tid + 1024];
    if (tid < 32) q3 = src[tid + 1536];
  };
  auto WRITEQ = [&](int buf) {
    float* Pb = P[buf];
    *(float4*)&Pb[c0a * PST + 4 * pq0] = q0;
    *(float4*)&Pb[c1a * PST + 4 * pq1] = q1;
    *(float4*)&Pb[c2a * PST + 4 * pq2] = q2;
    if (tid < 32) *(float4*)&Pb[c3a * PST + 4 * pq3] = q3;
  };

  // prologue: stage slice 0 (latency exposed once)
  LOADQ(sg * 4);
  WRITEQ(0);
  __syncthreads();

  for (int si = 0; si < 4; ++si) {
    const int s = sg * 4 + si;
    const int cur = si & 1;
    if (si < 3) LOADQ(s + 1);          // issue loads; consumed after compute below
    // transpose P[cur] -> xt: 7 tiles x 2 its x 64 lanes = 896 slots
#pragma unroll
    for (int pass = 0; pass < 2; ++pass) {
      int slot = tid + pass * 512;
      if (slot < 896) {
        int t = slot >> 7, r = slot & 127;
        int it = r >> 6, l = r & 63;
        int pxp = t * 32 + (l & 31);
        int row = pxp >> 4, col = pxp & 15;
        int c0 = it * 16 + (l >> 5) * 8;
        uint uu[4];
        if (col < 14) {
          int px = row * HIN + col;
#pragma unroll
          for (int p = 0; p < 4; ++p) {
            float v0 = P[cur][(c0 + 2 * p) * PST + px];
            float v1 = P[cur][(c0 + 2 * p + 1) * PST + px];
            uu[p] = (uint)__bfloat16_as_ushort(__float2bfloat16(v0)) |
                    ((uint)__bfloat16_as_ushort(__float2bfloat16(v1)) << 16);
          }
        } else {
          uu[0] = uu[1] = uu[2] = uu[3] = 0u;
        }
        uint4 pk; pk.x = uu[0]; pk.y = uu[1]; pk.z = uu[2]; pk.w = uu[3];
        *(uint4*)&xt[((((size_t)b * 7 + t) * 64 + s) * 1024) + it * 512 + (size_t)l * 8] = pk;
      }
    }
    // Gram from P[cur]
    {
      float xv[28];
      const float* Pr = &P[cur][chg * PST];
#pragma unroll
      for (int i = 0; i < 7; ++i) *(float4*)&xv[4 * i] = *(const float4*)&Pr[p0 + 4 * i];
#pragma unroll
      for (int p = 0; p < 13; ++p) {
        float a = xv[p];
        g[p][0] = fmaf(a, a, g[p][0]);
        g[p][1] = fmaf(a, xv[p + 1], g[p][1]);
        g[p][2] = fmaf(a, xv[p + 13], g[p][2]);
        g[p][3] = fmaf(a, xv[p + 14], g[p][3]);
        g[p][4] = fmaf(a, xv[p + 15], g[p][4]);
      }
    }
    if (si < 3) WRITEQ((si + 1) & 1);  // vmcnt wait lands here, after compute
    __syncthreads();                   // single barrier per si
  }

  // ---- Gram reduce: reuse P storage as Gw[8*16*65] (P is dead after the loop barrier) ----
  float* Gw = &P[0][0];
#pragma unroll
  for (int p = 0; p < 13; ++p)
#pragma unroll
    for (int t = 0; t < 5; ++t) {
      float v = g[p][t];
      v += __shfl_xor(v, 16, 64);
      v += __shfl_xor(v, 32, 64);
      g[p][t] = v;
    }
  if (lane < 16) {
#pragma unroll
    for (int p = 0; p < 13; ++p)
#pragma unroll
      for (int t = 0; t < 5; ++t) Gw[((size_t)wv * 16 + lane) * 65 + p * 5 + t] = g[p][t];
  }
  __syncthreads();
#pragma unroll
  for (int it = 0; it < 2; ++it) {
    int slot = tid + it * 512;
    if (slot < 16 * 65) {
      int sseg = slot / 65, i = slot - sseg * 65;
      float v = 0.f;
#pragma unroll
      for (int ww = 0; ww < 8; ++ww) v += Gw[((size_t)ww * 16 + sseg) * 65 + i];
      int pl = i / 5, ty = i - pl * 5;
      int px = sseg * 13 + pl;
      if (px < NPIX)
        Gpart[((size_t)b * 16 + sg) * (5 * GST) + ty * GST + px] = v;
    }
  }
}

// ---------------- K_gred ----------------
__global__ __launch_bounds__(256) void k_gred(const float* __restrict__ Gpart,
                                              float* __restrict__ Gs) {
  const int b = blockIdx.x, tid = threadIdx.x;
  for (int i = tid; i < 5 * GST; i += 256) {
    float v = 0.f;
#pragma unroll
    for (int sg = 0; sg < 16; ++sg) v += Gpart[((size_t)b * 16 + sg) * (5 * GST) + i];
    Gs[(size_t)b * (5 * GST) + i] = v;
  }
}

// ---------------- K_gemm3: 32x32x16 barrier-free MFMA + reg epilogue (unchanged, verified r13) ----
__global__ __launch_bounds__(256, 3) void k_gemm3(
    const ushort* __restrict__ xt,
    const ushort* __restrict__ cbf,
    const float* __restrict__ Gs,
    const float* __restrict__ csq,
    float* __restrict__ attn_out,
    float* __restrict__ part)
{
  __shared__ float RDs[128 * RDST];      // 34.8 KB
  __shared__ ushort Ssb[KDIM * SSTB];    // 13.6 KB
  __shared__ float csq_s[KDIM];
  __shared__ float xsqs[BNC], projs2[BNC];

  const int tid = threadIdx.x;
  const int wgid = blockIdx.x;
  const int xcd = wgid & 7, slot = wgid >> 3;
  const int bq = slot / NBX, bx = slot - bq * NBX;
  const int b = xcd + 8 * bq;
  const int n0 = bx * BNC;
  const int lane = tid & 63, w = tid >> 6;   // wave w = k-rows 32w..32w+31

  int r0 = bx - 1; if (r0 < 0) r0 = 0; if (r0 > 11) r0 = 11;
  const int T0 = r0 >> 1;                    // window = px' tiles T0, T0+1

  if (tid < KDIM) csq_s[tid] = csq[tid];

  const ushort* abp = cbf + w * 1024 + lane * 8;                    // + s*4096 + it*512
  const ushort* xtb = xt + (((size_t)b * 7 + T0) << 16) + lane * 8; // + tt*65536 + s*1024 + it*512

  f32x16 acc[2];
#pragma unroll
  for (int tt = 0; tt < 2; ++tt)
#pragma unroll
    for (int r = 0; r < 16; ++r) acc[tt][r] = 0.f;

#define LOADSET(A_, B_, S_)                                              \
  do {                                                                   \
    const size_t so_ = (size_t)(S_) * 4096;                              \
    const size_t xo_ = (size_t)(S_) * 1024;                              \
    A_[0] = *(const uint4*)(abp + so_);                                  \
    A_[1] = *(const uint4*)(abp + so_ + 512);                            \
    B_[0][0] = *(const uint4*)(xtb + xo_);                               \
    B_[0][1] = *(const uint4*)(xtb + xo_ + 512);                         \
    B_[1][0] = *(const uint4*)(xtb + 65536 + xo_);                       \
    B_[1][1] = *(const uint4*)(xtb + 65536 + xo_ + 512);                 \
  } while (0)

#define COMPUTE(A_, B_)                                                  \
  do {                                                                   \
    _Pragma("unroll")                                                    \
    for (int it_ = 0; it_ < 2; ++it_) {                                  \
      short8 af_ = *(const short8*)&A_[it_];                             \
      acc[0] = __builtin_amdgcn_mfma_f32_32x32x16_bf16(                  \
          af_, *(const short8*)&B_[0][it_], acc[0], 0, 0, 0);            \
      acc[1] = __builtin_amdgcn_mfma_f32_32x32x16_bf16(                  \
          af_, *(const short8*)&B_[1][it_], acc[1], 0, 0, 0);            \
    }                                                                    \
  } while (0)

  uint4 a0[2], a1[2], b0[2][2], b1[2][2];
  LOADSET(a0, b0, 0);
  for (int s = 0; s < NSTEP; s += 2) {
    if (s + 1 < NSTEP) LOADSET(a1, b1, s + 1);
    COMPUTE(a0, b0);
    if (s + 2 < NSTEP) LOADSET(a0, b0, s + 2);
    COMPUTE(a1, b1);
  }
#undef LOADSET
#undef COMPUTE

  // ---- RDs: 32x32 C/D layout col=lane&31, row=(r&3)+8*(r>>2)+4*(lane>>5) ----
#pragma unroll
  for (int tt = 0; tt < 2; ++tt)
#pragma unroll
    for (int r = 0; r < 16; ++r) {
      int row = w * 32 + (r & 3) + 8 * (r >> 2) + 4 * (lane >> 5);
      RDs[row * RDST + tt * 32 + (lane & 31)] = acc[tt][r];
    }
  __syncthreads();

  auto COLW = [&](int col, int& p1, int& p3, int& p1g, int& p3g,
                  float& w00, float& w01, float& w10, float& w11) {
    const int i2 = 2 * bx + (col >= 28 ? 1 : 0);
    const int j2 = col - (col >= 28 ? 28 : 0);
    float si = 0.5f * i2 - 0.25f, sj = 0.5f * j2 - 0.25f;
    float fif = floorf(si), fjf = floorf(sj);
    int ii = (int)fif, jj = (int)fjf;
    float fi = si - fif, fj = sj - fjf;
    int ia = ii < 0 ? 0 : ii; int ib = (ii + 1 > 13) ? 13 : ii + 1;
    int ja = jj < 0 ? 0 : jj; int jb = (jj + 1 > 13) ? 13 : jj + 1;
    w00 = (1.f - fi) * (1.f - fj); w01 = (1.f - fi) * fj;
    w10 = fi * (1.f - fj);         w11 = fi * fj;
    if (ib == ia) { w00 += w10; w01 += w11; w10 = 0.f; w11 = 0.f; }
    if (jb == ja) { w00 += w01; w10 += w11; w01 = 0.f; w11 = 0.f; }
    p1g = ia * HIN + ja; p3g = ib * HIN + ja;
    p1 = ia * 16 + ja - T0 * 32; p3 = ib * 16 + ja - T0 * 32;
  };

  // ---- xsq (Gram blend) + raw proj (RDs row 113) ----
  if (tid < BNC) {
    int p1, p3, p1g, p3g; float w00, w01, w10, w11;
    COLW(tid, p1, p3, p1g, p3g, w00, w01, w10, w11);
    const float* Gb = Gs + (size_t)b * (5 * GST);
    const float* Gd = Gb, *Gr = Gb + GST, *Gy = Gb + 2 * GST, *Gv = Gb + 3 * GST, *Gx = Gb + 4 * GST;
    float xsq = w00 * w00 * Gd[p1g] + w01 * w01 * Gd[p1g + 1]
              + w10 * w10 * Gd[p3g] + w11 * w11 * Gd[p3g + 1]
              + 2.f * (w00 * w01 * Gr[p1g] + w10 * w11 * Gr[p3g]
                     + w00 * w10 * Gv[p1g] + w01 * w11 * Gv[p1g + 1]
                     + w00 * w11 * Gx[p1g] + w01 * w10 * Gy[p1g + 1]);
    const float* rp = &RDs[113 * RDST];
    float pj = w00 * rp[p1] + w01 * rp[p1 + 1] + w10 * rp[p3] + w11 * rp[p3 + 1];
    xsqs[tid] = xsq; projs2[tid] = pj;
  }
  __syncthreads();

  // ---- dist (regs) -> quad softmax -> attn write (local rinv) + Ssb ----
  if (tid < BNC * 4) {
    const int col = tid >> 2, sub = tid & 3;
    int p1, p3, p1g, p3g; float w00, w01, w10, w11;
    COLW(col, p1, p3, p1g, p3g, w00, w01, w10, w11);
    const float xq = xsqs[col];
    float ev[29];
    float mx = -1e30f;
#pragma unroll
    for (int i = 0; i < 29; ++i) {
      int k = sub + 4 * i;
      if (k < KDIM) {
        const float* rk = &RDs[k * RDST];
        float dot = w00 * rk[p1] + w01 * rk[p1 + 1] + w10 * rk[p3] + w11 * rk[p3 + 1];
        float d2 = csq_s[k] + xq - 2.f * dot;
        float sv = -sqrtf(fmaxf(d2, 0.f));
        ev[i] = sv;
        mx = fmaxf(mx, sv);
      }
    }
    mx = fmaxf(mx, __shfl_xor(mx, 1, 64));
    mx = fmaxf(mx, __shfl_xor(mx, 2, 64));
    float ssum = 0.f;
#pragma unroll
    for (int i = 0; i < 29; ++i) {
      int k = sub + 4 * i;
      if (k < KDIM) {
        float e = __expf(ev[i] - mx);
        ev[i] = e;
        Ssb[k * SSTB + col] = __bfloat16_as_ushort(__float2bfloat16(e));
        ssum += e;
      }
    }
    ssum += __shfl_xor(ssum, 1, 64);
    ssum += __shfl_xor(ssum, 2, 64);
    const float rinv = 1.f / ssum;
    float* op = attn_out + (size_t)b * KDIM * N2 + n0 + col;
#pragma unroll
    for (int i = 0; i < 29; ++i) {
      int k = sub + 4 * i;
      if (k < KDIM) op[(size_t)k * N2] = ev[i] * rinv;
    }
    if (sub == 0) projs2[col] *= rinv;
  }
  __syncthreads();   // uniform barrier

  // ---- logit partials ----
  if (tid < KC * 2) {
    const int k = tid >> 1, s2 = tid & 1;
    float lg = 0.f;
    for (int c2 = s2; c2 < BNC; c2 += 2)
      lg = fmaf(__uint_as_float((uint)Ssb[k * SSTB + c2] << 16), projs2[c2], lg);
    lg += __shfl_xor(lg, 1, 64);
    if (s2 == 0) part[((size_t)b * NBX + bx) * KC + k] = lg;
  }
}

// ---------------- K_tmp (+sig fused) ----------------
__global__ __launch_bounds__(256) void k_tmp(
    const float* __restrict__ concepts, const float* __restrict__ part,
    const float* __restrict__ cfcb, float* __restrict__ cs_out,
    float* __restrict__ tmp) {
  __shared__ float cs_s[KC];
  const int b = blockIdx.y, cx = blockIdx.x;
  const int t = threadIdx.x;
  if (t < KC) {
    float l = cfcb[0];
#pragma unroll
    for (int q = 0; q < NBX; ++q) l += part[((size_t)b * NBX + q) * KC + t];
    float csv = 1.f / (1.f + __expf(-l));
    cs_s[t] = csv;
    if (cx == 0) cs_out[b * KC + t] = csv;
  }
  __syncthreads();
  const int c = cx * 256 + t;
  float a = 0.f;
#pragma unroll 8
  for (int k = 0; k < KC; ++k) a = fmaf(cs_s[k], concepts[(size_t)k * CDIM + c], a);
  tmp[(size_t)b * CDIM + c] = a;
}

// ---------------- K5b: preds ----------------
__global__ __launch_bounds__(256) void k_pred2(
    const float* __restrict__ labw, const float* __restrict__ labb,
    const float* __restrict__ tmp, float* __restrict__ preds) {
  const int w = blockIdx.x * 4 + (threadIdx.x >> 6);
  const int lane = threadIdx.x & 63;
  const int b = w / NCLS, cls = w % NCLS;
  if (b >= BDIM) return;
  const float* tr = tmp + (size_t)b * CDIM;
  const float* wr = labw + (size_t)cls * CDIM;
  float a = 0.f;
#pragma unroll
  for (int c0 = 0; c0 < CDIM; c0 += 256) {
    float4 t = *(const float4*)&tr[c0 + lane * 4];
    float4 v = *(const float4*)&wr[c0 + lane * 4];
    a += t.x * v.x + t.y * v.y + t.z * v.z + t.w * v.w;
  }
#pragma unroll
  for (int off = 32; off > 0; off >>= 1) a += __shfl_down(a, off, 64);
  if (lane == 0) preds[b * NCLS + cls] = a + labb[cls];
}

extern "C" void kernel_launch(void* const* d_in, const int* in_sizes, int n_in,
                              void* d_out, int out_size, void* d_ws, size_t ws_size,
                              hipStream_t stream) {
  const float* x        = (const float*)d_in[0];
  const float* concepts = (const float*)d_in[1];
  const float* cfcw     = (const float*)d_in[2];
  const float* cfcb     = (const float*)d_in[3];
  const float* labw     = (const float*)d_in[4];
  const float* labb     = (const float*)d_in[5];

  float* out    = (float*)d_out;
  float* sm_out = out;                                  // [32][113][784]
  float* cs_out = out + (size_t)BDIM * KDIM * N2;       // [32][112]
  float* pr_out = cs_out + (size_t)BDIM * KC;           // [32][200]

  char* ws = (char*)d_ws;
  float*  csq   = (float*)(ws + 0);          // 128 f32             512 B
  float*  part  = (float*)(ws + 512);        // 32*14*112 f32       200,704 B
  ushort* cbf   = (ushort*)(ws + 201216);    // 128*2048 bf16       524,288 B
  float*  tmp   = (float*)(ws + 725504);     // 32*2048 f32         262,144 B
  float*  Gpart = (float*)(ws + 987648);     // 32*16*1000 f32      2,048,000 B
  float*  Gs    = (float*)(ws + 3035648);    // 32*1000 f32         128,000 B
  ushort* xt    = (ushort*)(ws + 3163648);   // 32*7*64*1024 bf16   29,360,128 B

  k_prep <<<dim3(128), dim3(256), 0, stream>>>(concepts, cfcw, cbf, csq);
  k_xt   <<<dim3(16, BDIM), dim3(512), 0, stream>>>(x, xt, Gpart);
  k_gred <<<dim3(BDIM), dim3(256), 0, stream>>>(Gpart, Gs);
  k_gemm3<<<dim3(448), dim3(256), 0, stream>>>(xt, cbf, Gs, csq, sm_out, part);
  k_tmp  <<<dim3(CDIM / 256, BDIM), dim3(256), 0, stream>>>(concepts, part, cfcb, cs_out, tmp);
  k_pred2<<<dim3((BDIM * NCLS + 3) / 4), dim3(256), 0, stream>>>(labw, labb, tmp, pr_out);
}

// Round 15
// 84.572 us; speedup vs baseline: 1.2704x; 1.0016x over previous
//
#include <hip/hip_runtime.h>
#include <hip/hip_bf16.h>
#include <cstdint>

typedef __attribute__((ext_vector_type(8))) short short8;
typedef __attribute__((ext_vector_type(4))) float f32x4;
typedef __attribute__((ext_vector_type(16))) float f32x16;

#define BDIM 32
#define CDIM 2048
#define NPIX 196    // 14*14
#define HIN 14
#define N2 784      // 28*28
#define W2 28
#define KDIM 113
#define KC 112
#define NCLS 200
#define NBX 14      // col-blocks per image (2 output rows each)
#define BNC 56      // output cols per block
#define NSTEP 64    // 2048/32
#define PST 224     // k_xt staged plane stride (196 + 28 pad)
#define GST 200     // Gram per-type stride
#define RDST 68     // RDs row stride (f32)
#define SSTB 60     // Ssb row stride (ushort)

// ---------------- K_prep: concepts (+cfcw row 113) -> bf16 in 32x32x16 A-fragment order + csq ----
__global__ __launch_bounds__(256) void k_prep(const float* __restrict__ concepts,
                                              const float* __restrict__ cfcw,
                                              ushort* __restrict__ cbf,
                                              float* __restrict__ csq) {
  int k = blockIdx.x, t = threadIdx.x;
  const int kt = k >> 5, row = k & 31;
  float s = 0.f;
  for (int c = t; c < CDIM; c += 256) {
    float v = (k < KDIM) ? concepts[(size_t)k * CDIM + c] : (k == KDIM ? cfcw[c] : 0.f);
    __hip_bfloat16 h = __float2bfloat16(v);
    int st = c >> 5, it = (c >> 4) & 1, g2 = (c >> 3) & 1, j = c & 7;
    cbf[(((size_t)st * 4 + kt) * 2 + it) * 512 + (g2 * 32 + row) * 8 + j] = __bfloat16_as_ushort(h);
    float vb = __bfloat162float(h);
    s = fmaf(vb, vb, s);
  }
  __shared__ float r[4];
#pragma unroll
  for (int off = 32; off > 0; off >>= 1) s += __shfl_down(s, off, 64);
  if ((t & 63) == 0) r[t >> 6] = s;
  __syncthreads();
  if (t == 0) csq[k] = r[0] + r[1] + r[2] + r[3];
}

// ---------------- K_xt: async-split, double-buffered transpose + Gram ----------------
// Per si: issue loads(si+1) -> transpose+Gram(P[cur]) -> write regs->P[nxt] -> 1 barrier.
__global__ __launch_bounds__(512, 4) void k_xt(const float* __restrict__ x,
                                               ushort* __restrict__ xt,
                                               float* __restrict__ Gpart) {
  __shared__ float P[2][32 * PST];     // 57.3 KB double-buffered; reused as Gw after loop
  const int sg = blockIdx.x, b = blockIdx.y;
  const int tid = threadIdx.x;
  const int lane = tid & 63, wv = tid >> 6;
  const int chg = tid >> 4, seg = tid & 15;
  const int p0 = seg * 13;

  // staging index precompute (1568 float4 per slice; thread covers 3 [+1 if tid<32])
  const int c0a = tid / 49,           pq0 = tid - c0a * 49;
  const int c1a = (tid + 512) / 49,   pq1 = (tid + 512) - c1a * 49;
  const int c2a = (tid + 1024) / 49,  pq2 = (tid + 1024) - c2a * 49;
  const int c3a = (tid + 1536) / 49,  pq3 = (tid + 1536) - c3a * 49;  // tid<32 only

  // zero pads in BOTH buffers: P[buf][c][196..223]
  for (int z = tid; z < 2 * 32 * 28; z += 512) {
    int buf = z / 896, r = z - buf * 896;
    int c = r / 28, j = r - c * 28;
    P[buf][c * PST + 196 + j] = 0.f;
  }

  float g[13][5];
#pragma unroll
  for (int p = 0; p < 13; ++p)
#pragma unroll
    for (int t = 0; t < 5; ++t) g[p][t] = 0.f;

  float4 q0, q1, q2, q3 = {0.f, 0.f, 0.f, 0.f};
  auto LOADQ = [&](int s) {
    const float4* src = (const float4*)(x + ((size_t)b * CDIM + s * 32) * NPIX);
    q0 = src[tid]; q1 = src[tid + 512]; q2 = src[tid + 1024];
    if (tid < 32) q3 = src[tid + 1536];
  };
  auto WRITEQ = [&](int buf) {
    float* Pb = P[buf];
    *(float4*)&Pb[c0a * PST + 4 * pq0] = q0;
    *(float4*)&Pb[c1a * PST + 4 * pq1] = q1;
    *(float4*)&Pb[c2a * PST + 4 * pq2] = q2;
    if (tid < 32) *(float4*)&Pb[c3a * PST + 4 * pq3] = q3;
  };

  // prologue: stage slice 0 (latency exposed once)
  LOADQ(sg * 4);
  WRITEQ(0);
  __syncthreads();

  for (int si = 0; si < 4; ++si) {
    const int s = sg * 4 + si;
    const int cur = si & 1;
    if (si < 3) LOADQ(s + 1);          // issue loads; consumed after compute below
    // transpose P[cur] -> xt: 7 tiles x 2 its x 64 lanes = 896 slots
#pragma unroll
    for (int pass = 0; pass < 2; ++pass) {
      int slot = tid + pass * 512;
      if (slot < 896) {
        int t = slot >> 7, r = slot & 127;
        int it = r >> 6, l = r & 63;
        int pxp = t * 32 + (l & 31);
        int row = pxp >> 4, col = pxp & 15;
        int c0 = it * 16 + (l >> 5) * 8;
        uint uu[4];
        if (col < 14) {
          int px = row * HIN + col;
#pragma unroll
          for (int p = 0; p < 4; ++p) {
            float v0 = P[cur][(c0 + 2 * p) * PST + px];
            float v1 = P[cur][(c0 + 2 * p + 1) * PST + px];
            uu[p] = (uint)__bfloat16_as_ushort(__float2bfloat16(v0)) |
                    ((uint)__bfloat16_as_ushort(__float2bfloat16(v1)) << 16);
          }
        } else {
          uu[0] = uu[1] = uu[2] = uu[3] = 0u;
        }
        uint4 pk; pk.x = uu[0]; pk.y = uu[1]; pk.z = uu[2]; pk.w = uu[3];
        *(uint4*)&xt[((((size_t)b * 7 + t) * 64 + s) * 1024) + it * 512 + (size_t)l * 8] = pk;
      }
    }
    // Gram from P[cur]
    {
      float xv[28];
      const float* Pr = &P[cur][chg * PST];
#pragma unroll
      for (int i = 0; i < 7; ++i) *(float4*)&xv[4 * i] = *(const float4*)&Pr[p0 + 4 * i];
#pragma unroll
      for (int p = 0; p < 13; ++p) {
        float a = xv[p];
        g[p][0] = fmaf(a, a, g[p][0]);
        g[p][1] = fmaf(a, xv[p + 1], g[p][1]);
        g[p][2] = fmaf(a, xv[p + 13], g[p][2]);
        g[p][3] = fmaf(a, xv[p + 14], g[p][3]);
        g[p][4] = fmaf(a, xv[p + 15], g[p][4]);
      }
    }
    if (si < 3) WRITEQ((si + 1) & 1);  // vmcnt wait lands here, after compute
    __syncthreads();                   // single barrier per si
  }

  // ---- Gram reduce: reuse P storage as Gw[8*16*65] (P is dead after the loop barrier) ----
  float* Gw = &P[0][0];
#pragma unroll
  for (int p = 0; p < 13; ++p)
#pragma unroll
    for (int t = 0; t < 5; ++t) {
      float v = g[p][t];
      v += __shfl_xor(v, 16, 64);
      v += __shfl_xor(v, 32, 64);
      g[p][t] = v;
    }
  if (lane < 16) {
#pragma unroll
    for (int p = 0; p < 13; ++p)
#pragma unroll
      for (int t = 0; t < 5; ++t) Gw[((size_t)wv * 16 + lane) * 65 + p * 5 + t] = g[p][t];
  }
  __syncthreads();
#pragma unroll
  for (int it = 0; it < 2; ++it) {
    int slot = tid + it * 512;
    if (slot < 16 * 65) {
      int sseg = slot / 65, i = slot - sseg * 65;
      float v = 0.f;
#pragma unroll
      for (int ww = 0; ww < 8; ++ww) v += Gw[((size_t)ww * 16 + sseg) * 65 + i];
      int pl = i / 5, ty = i - pl * 5;
      int px = sseg * 13 + pl;
      if (px < NPIX)
        Gpart[((size_t)b * 16 + sg) * (5 * GST) + ty * GST + px] = v;
    }
  }
}

// ---------------- K_gred ----------------
__global__ __launch_bounds__(256) void k_gred(const float* __restrict__ Gpart,
                                              float* __restrict__ Gs) {
  const int b = blockIdx.x, tid = threadIdx.x;
  for (int i = tid; i < 5 * GST; i += 256) {
    float v = 0.f;
#pragma unroll
    for (int sg = 0; sg < 16; ++sg) v += Gpart[((size_t)b * 16 + sg) * (5 * GST) + i];
    Gs[(size_t)b * (5 * GST) + i] = v;
  }
}

// ---------------- K_gemm3: 32x32x16 barrier-free MFMA + reg epilogue (unchanged, verified r13) ----
__global__ __launch_bounds__(256, 3) void k_gemm3(
    const ushort* __restrict__ xt,
    const ushort* __restrict__ cbf,
    const float* __restrict__ Gs,
    const float* __restrict__ csq,
    float* __restrict__ attn_out,
    float* __restrict__ part)
{
  __shared__ float RDs[128 * RDST];      // 34.8 KB
  __shared__ ushort Ssb[KDIM * SSTB];    // 13.6 KB
  __shared__ float csq_s[KDIM];
  __shared__ float xsqs[BNC], projs2[BNC];

  const int tid = threadIdx.x;
  const int wgid = blockIdx.x;
  const int xcd = wgid & 7, slot = wgid >> 3;
  const int bq = slot / NBX, bx = slot - bq * NBX;
  const int b = xcd + 8 * bq;
  const int n0 = bx * BNC;
  const int lane = tid & 63, w = tid >> 6;   // wave w = k-rows 32w..32w+31

  int r0 = bx - 1; if (r0 < 0) r0 = 0; if (r0 > 11) r0 = 11;
  const int T0 = r0 >> 1;                    // window = px' tiles T0, T0+1

  if (tid < KDIM) csq_s[tid] = csq[tid];

  const ushort* abp = cbf + w * 1024 + lane * 8;                    // + s*4096 + it*512
  const ushort* xtb = xt + (((size_t)b * 7 + T0) << 16) + lane * 8; // + tt*65536 + s*1024 + it*512

  f32x16 acc[2];
#pragma unroll
  for (int tt = 0; tt < 2; ++tt)
#pragma unroll
    for (int r = 0; r < 16; ++r) acc[tt][r] = 0.f;

#define LOADSET(A_, B_, S_)                                              \
  do {                                                                   \
    const size_t so_ = (size_t)(S_) * 4096;                              \
    const size_t xo_ = (size_t)(S_) * 1024;                              \
    A_[0] = *(const uint4*)(abp + so_);                                  \
    A_[1] = *(const uint4*)(abp + so_ + 512);                            \
    B_[0][0] = *(const uint4*)(xtb + xo_);                               \
    B_[0][1] = *(const uint4*)(xtb + xo_ + 512);                         \
    B_[1][0] = *(const uint4*)(xtb + 65536 + xo_);                       \
    B_[1][1] = *(const uint4*)(xtb + 65536 + xo_ + 512);                 \
  } while (0)

#define COMPUTE(A_, B_)                                                  \
  do {                                                                   \
    _Pragma("unroll")                                                    \
    for (int it_ = 0; it_ < 2; ++it_) {                                  \
      short8 af_ = *(const short8*)&A_[it_];                             \
      acc[0] = __builtin_amdgcn_mfma_f32_32x32x16_bf16(                  \
          af_, *(const short8*)&B_[0][it_], acc[0], 0, 0, 0);            \
      acc[1] = __builtin_amdgcn_mfma_f32_32x32x16_bf16(                  \
          af_, *(const short8*)&B_[1][it_], acc[1], 0, 0, 0);            \
    }                                                                    \
  } while (0)

  uint4 a0[2], a1[2], b0[2][2], b1[2][2];
  LOADSET(a0, b0, 0);
  for (int s = 0; s < NSTEP; s += 2) {
    if (s + 1 < NSTEP) LOADSET(a1, b1, s + 1);
    COMPUTE(a0, b0);
    if (s + 2 < NSTEP) LOADSET(a0, b0, s + 2);
    COMPUTE(a1, b1);
  }
#undef LOADSET
#undef COMPUTE

  // ---- RDs: 32x32 C/D layout col=lane&31, row=(r&3)+8*(r>>2)+4*(lane>>5) ----
#pragma unroll
  for (int tt = 0; tt < 2; ++tt)
#pragma unroll
    for (int r = 0; r < 16; ++r) {
      int row = w * 32 + (r & 3) + 8 * (r >> 2) + 4 * (lane >> 5);
      RDs[row * RDST + tt * 32 + (lane & 31)] = acc[tt][r];
    }
  __syncthreads();

  auto COLW = [&](int col, int& p1, int& p3, int& p1g, int& p3g,
                  float& w00, float& w01, float& w10, float& w11) {
    const int i2 = 2 * bx + (col >= 28 ? 1 : 0);
    const int j2 = col - (col >= 28 ? 28 : 0);
    float si = 0.5f * i2 - 0.25f, sj = 0.5f * j2 - 0.25f;
    float fif = floorf(si), fjf = floorf(sj);
    int ii = (int)fif, jj = (int)fjf;
    float fi = si - fif, fj = sj - fjf;
    int ia = ii < 0 ? 0 : ii; int ib = (ii + 1 > 13) ? 13 : ii + 1;
    int ja = jj < 0 ? 0 : jj; int jb = (jj + 1 > 13) ? 13 : jj + 1;
    w00 = (1.f - fi) * (1.f - fj); w01 = (1.f - fi) * fj;
    w10 = fi * (1.f - fj);         w11 = fi * fj;
    if (ib == ia) { w00 += w10; w01 += w11; w10 = 0.f; w11 = 0.f; }
    if (jb == ja) { w00 += w01; w10 += w11; w01 = 0.f; w11 = 0.f; }
    p1g = ia * HIN + ja; p3g = ib * HIN + ja;
    p1 = ia * 16 + ja - T0 * 32; p3 = ib * 16 + ja - T0 * 32;
  };

  // ---- xsq (Gram blend) + raw proj (RDs row 113) ----
  if (tid < BNC) {
    int p1, p3, p1g, p3g; float w00, w01, w10, w11;
    COLW(tid, p1, p3, p1g, p3g, w00, w01, w10, w11);
    const float* Gb = Gs + (size_t)b * (5 * GST);
    const float* Gd = Gb, *Gr = Gb + GST, *Gy = Gb + 2 * GST, *Gv = Gb + 3 * GST, *Gx = Gb + 4 * GST;
    float xsq = w00 * w00 * Gd[p1g] + w01 * w01 * Gd[p1g + 1]
              + w10 * w10 * Gd[p3g] + w11 * w11 * Gd[p3g + 1]
              + 2.f * (w00 * w01 * Gr[p1g] + w10 * w11 * Gr[p3g]
                     + w00 * w10 * Gv[p1g] + w01 * w11 * Gv[p1g + 1]
                     + w00 * w11 * Gx[p1g] + w01 * w10 * Gy[p1g + 1]);
    const float* rp = &RDs[113 * RDST];
    float pj = w00 * rp[p1] + w01 * rp[p1 + 1] + w10 * rp[p3] + w11 * rp[p3 + 1];
    xsqs[tid] = xsq; projs2[tid] = pj;
  }
  __syncthreads();

  // ---- dist (regs) -> quad softmax -> attn write (local rinv) + Ssb ----
  if (tid < BNC * 4) {
    const int col = tid >> 2, sub = tid & 3;
    int p1, p3, p1g, p3g; float w00, w01, w10, w11;
    COLW(col, p1, p3, p1g, p3g, w00, w01, w10, w11);
    const float xq = xsqs[col];
    float ev[29];
    float mx = -1e30f;
#pragma unroll
    for (int i = 0; i < 29; ++i) {
      int k = sub + 4 * i;
      if (k < KDIM) {
        const float* rk = &RDs[k * RDST];
        float dot = w00 * rk[p1] + w01 * rk[p1 + 1] + w10 * rk[p3] + w11 * rk[p3 + 1];
        float d2 = csq_s[k] + xq - 2.f * dot;
        float sv = -sqrtf(fmaxf(d2, 0.f));
        ev[i] = sv;
        mx = fmaxf(mx, sv);
      }
    }
    mx = fmaxf(mx, __shfl_xor(mx, 1, 64));
    mx = fmaxf(mx, __shfl_xor(mx, 2, 64));
    float ssum = 0.f;
#pragma unroll
    for (int i = 0; i < 29; ++i) {
      int k = sub + 4 * i;
      if (k < KDIM) {
        float e = __expf(ev[i] - mx);
        ev[i] = e;
        Ssb[k * SSTB + col] = __bfloat16_as_ushort(__float2bfloat16(e));
        ssum += e;
      }
    }
    ssum += __shfl_xor(ssum, 1, 64);
    ssum += __shfl_xor(ssum, 2, 64);
    const float rinv = 1.f / ssum;
    float* op = attn_out + (size_t)b * KDIM * N2 + n0 + col;
#pragma unroll
    for (int i = 0; i < 29; ++i) {
      int k = sub + 4 * i;
      if (k < KDIM) op[(size_t)k * N2] = ev[i] * rinv;
    }
    if (sub == 0) projs2[col] *= rinv;
  }
  __syncthreads();   // uniform barrier

  // ---- logit partials ----
  if (tid < KC * 2) {
    const int k = tid >> 1, s2 = tid & 1;
    float lg = 0.f;
    for (int c2 = s2; c2 < BNC; c2 += 2)
      lg = fmaf(__uint_as_float((uint)Ssb[k * SSTB + c2] << 16), projs2[c2], lg);
    lg += __shfl_xor(lg, 1, 64);
    if (s2 == 0) part[((size_t)b * NBX + bx) * KC + k] = lg;
  }
}

// ---------------- K_tmp (+sig fused) ----------------
__global__ __launch_bounds__(256) void k_tmp(
    const float* __restrict__ concepts, const float* __restrict__ part,
    const float* __restrict__ cfcb, float* __restrict__ cs_out,
    float* __restrict__ tmp) {
  __shared__ float cs_s[KC];
  const int b = blockIdx.y, cx = blockIdx.x;
  const int t = threadIdx.x;
  if (t < KC) {
    float l = cfcb[0];
#pragma unroll
    for (int q = 0; q < NBX; ++q) l += part[((size_t)b * NBX + q) * KC + t];
    float csv = 1.f / (1.f + __expf(-l));
    cs_s[t] = csv;
    if (cx == 0) cs_out[b * KC + t] = csv;
  }
  __syncthreads();
  const int c = cx * 256 + t;
  float a = 0.f;
#pragma unroll 8
  for (int k = 0; k < KC; ++k) a = fmaf(cs_s[k], concepts[(size_t)k * CDIM + c], a);
  tmp[(size_t)b * CDIM + c] = a;
}

// ---------------- K5b: preds ----------------
__global__ __launch_bounds__(256) void k_pred2(
    const float* __restrict__ labw, const float* __restrict__ labb,
    const float* __restrict__ tmp, float* __restrict__ preds) {
  const int w = blockIdx.x * 4 + (threadIdx.x >> 6);
  const int lane = threadIdx.x & 63;
  const int b = w / NCLS, cls = w % NCLS;
  if (b >= BDIM) return;
  const float* tr = tmp + (size_t)b * CDIM;
  const float* wr = labw + (size_t)cls * CDIM;
  float a = 0.f;
#pragma unroll
  for (int c0 = 0; c0 < CDIM; c0 += 256) {
    float4 t = *(const float4*)&tr[c0 + lane * 4];
    float4 v = *(const float4*)&wr[c0 + lane * 4];
    a += t.x * v.x + t.y * v.y + t.z * v.z + t.w * v.w;
  }
#pragma unroll
  for (int off = 32; off > 0; off >>= 1) a += __shfl_down(a, off, 64);
  if (lane == 0) preds[b * NCLS + cls] = a + labb[cls];
}

extern "C" void kernel_launch(void* const* d_in, const int* in_sizes, int n_in,
                              void* d_out, int out_size, void* d_ws, size_t ws_size,
                              hipStream_t stream) {
  const float* x        = (const float*)d_in[0];
  const float* concepts = (const float*)d_in[1];
  const float* cfcw     = (const float*)d_in[2];
  const float* cfcb     = (const float*)d_in[3];
  const float* labw     = (const float*)d_in[4];
  const float* labb     = (const float*)d_in[5];

  float* out    = (float*)d_out;
  float* sm_out = out;                                  // [32][113][784]
  float* cs_out = out + (size_t)BDIM * KDIM * N2;       // [32][112]
  float* pr_out = cs_out + (size_t)BDIM * KC;           // [32][200]

  char* ws = (char*)d_ws;
  float*  csq   = (float*)(ws + 0);          // 128 f32             512 B
  float*  part  = (float*)(ws + 512);        // 32*14*112 f32       200,704 B
  ushort* cbf   = (ushort*)(ws + 201216);    // 128*2048 bf16       524,288 B
  float*  tmp   = (float*)(ws + 725504);     // 32*2048 f32         262,144 B
  float*  Gpart = (float*)(ws + 987648);     // 32*16*1000 f32      2,048,000 B
  float*  Gs    = (float*)(ws + 3035648);    // 32*1000 f32         128,000 B
  ushort* xt    = (ushort*)(ws + 3163648);   // 32*7*64*1024 bf16   29,360,128 B

  k_prep <<<dim3(128), dim3(256), 0, stream>>>(concepts, cfcw, cbf, csq);
  k_xt   <<<dim3(16, BDIM), dim3(512), 0, stream>>>(x, xt, Gpart);
  k_gred <<<dim3(BDIM), dim3(256), 0, stream>>>(Gpart, Gs);
  k_gemm3<<<dim3(448), dim3(256), 0, stream>>>(xt, cbf, Gs, csq, sm_out, part);
  k_tmp  <<<dim3(CDIM / 256, BDIM), dim3(256), 0, stream>>>(concepts, part, cfcb, cs_out, tmp);
  k_pred2<<<dim3((BDIM * NCLS + 3) / 4), dim3(256), 0, stream>>>(labw, labb, tmp, pr_out);
}